// Round 5
// baseline (3368.534 us; speedup 1.0000x reference)
//
#include <hip/hip_runtime.h>
#include <hip/hip_cooperative_groups.h>

namespace cg = cooperative_groups;

// out[token][0:64] = relu(W[x[token]][0:64] + b[0:64]) + 1e-5
// x: int32 [4194304], W: f32 [100000][64], b: f32 [64], out: f32 [4194304][64]
//
// Pass-synchronized category-range gather:
//  - each block owns 2048 tokens; stages x-slab in LDS (read once)
//  - bucket-sorts token ids by category chunk (idx>>13) in LDS -> no rescan
//  - 13 passes; pass p gathers only from W rows [p*8192,(p+1)*8192) = 2 MB,
//    which fits each XCD's 4 MB L2
//  - grid.sync() between passes keeps ALL blocks on the same pass, so the
//    2 MB chunk actually stays pinned (R3 failed from inter-block pass skew)
//  - nontemporal stores keep the 1 GB output stream from evicting W

typedef float f32x4 __attribute__((ext_vector_type(4)));

#define TPB 2048                 // tokens per block
#define CAT_SHIFT 13             // 8192 categories = 2 MB f32 chunk
#define NPASS 13                 // ceil(100000 / 8192)

__global__ __launch_bounds__(256, 8) void gather_bias_relu_kernel(
    const int* __restrict__ x,
    const f32x4* __restrict__ W4,    // [100000][16]
    const f32x4* __restrict__ b4,    // [16]
    f32x4* __restrict__ out4,        // [ntok][16]
    int ntok)
{
    __shared__ int            s_idx[TPB];        // 8 KB
    __shared__ unsigned short s_tok[TPB];        // 4 KB
    __shared__ int            s_cnt[NPASS + 1];
    __shared__ int            s_ofs[NPASS];

    cg::grid_group grid = cg::this_grid();

    const int       tid  = threadIdx.x;
    const long long base = (long long)blockIdx.x * TPB;
    const int       nblk = (int)min((long long)TPB, (long long)ntok - base);

    if (tid < NPASS + 1) s_cnt[tid] = 0;
    __syncthreads();

    // Stage x-slab + histogram by category chunk.
    for (int i = tid; i < nblk; i += 256) {
        const int v = x[base + i];
        s_idx[i] = v;
        atomicAdd(&s_cnt[(v >> CAT_SHIFT) + 1], 1);
    }
    __syncthreads();

    // Inclusive scan -> s_cnt[p] = start of bucket p, s_cnt[NPASS] = nblk.
    if (tid == 0) {
        int acc = 0;
        #pragma unroll
        for (int p = 0; p <= NPASS; ++p) { acc += s_cnt[p]; s_cnt[p] = acc; }
    }
    __syncthreads();
    if (tid < NPASS) s_ofs[tid] = s_cnt[tid];
    __syncthreads();

    // Scatter token ids into bucket order.
    for (int i = tid; i < nblk; i += 256) {
        const int bkt = s_idx[i] >> CAT_SHIFT;
        const int pos = atomicAdd(&s_ofs[bkt], 1);
        s_tok[pos] = (unsigned short)i;
    }
    __syncthreads();

    const int   j     = tid & 15;         // 16B slot within the 64-float row
    const f32x4 bias  = b4[j];
    const int   group = tid >> 4;         // 16 token-groups per block

    for (int pass = 0; pass < NPASS; ++pass) {
        const int s = s_cnt[pass];
        const int e = s_cnt[pass + 1];
        #pragma unroll 2
        for (int i = s + group; i < e; i += 16) {
            const int t   = s_tok[i];
            const int idx = s_idx[t];
            f32x4 w = W4[(size_t)idx * 16 + j];
            f32x4 r;
            #pragma unroll
            for (int c = 0; c < 4; ++c)
                r[c] = fmaxf(w[c] + bias[c], 0.0f) + 1e-5f;
            __builtin_nontemporal_store(r, &out4[(base + t) * 16 + j]);
        }
        if (pass < NPASS - 1) grid.sync();   // keep all blocks on same W chunk
    }
}

extern "C" void kernel_launch(void* const* d_in, const int* in_sizes, int n_in,
                              void* d_out, int out_size, void* d_ws, size_t ws_size,
                              hipStream_t stream) {
    const int*   x   = (const int*)d_in[0];
    const f32x4* W   = (const f32x4*)d_in[1];
    const f32x4* b   = (const f32x4*)d_in[2];
    f32x4*       out = (f32x4*)d_out;
    int          ntok = in_sizes[0];       // 4,194,304

    const int grid_blocks = (ntok + TPB - 1) / TPB;   // 2048 = exact GPU fill

    void* args[] = { (void*)&x, (void*)&W, (void*)&b, (void*)&out, (void*)&ntok };
    hipLaunchCooperativeKernel((const void*)gather_bias_relu_kernel,
                               dim3(grid_blocks), dim3(256), args, 0, stream);
}

// Round 6
// 696.416 us; speedup vs baseline: 4.8370x; 4.8370x over previous
//
#include <hip/hip_runtime.h>

// out[token][0:64] = relu(W[x[token]][0:64] + b[0:64]) + 1e-5
// x: int32 [4194304], W: f32 [100000][64], b: f32 [64], out: f32 [4194304][64]
//
// Static XCD-chunk ownership (no sync): categories split into 16 chunks of
// 6250 rows (1.6 MB). XCD x owns chunks {x, x+8} (3.2 MB, pinned in its 4 MB
// L2 for the whole kernel). Blocks land on XCD blockIdx%8 (round-robin
// dispatch). Each XCD's 256 blocks partition the token stream; a block scans
// its 16384-token span and processes only tokens whose category falls in its
// XCD's chunks. Every token is handled by exactly one XCD; W gathers are
// L2-hits after first touch. x loads and out stores are nontemporal so the
// two streams don't evict the pinned W chunks.
// (R5 proved pinning works: FETCH 1.8GB->110MB; grid.sync was the 3ms cost.)

typedef float f32x4 __attribute__((ext_vector_type(4)));

#define NCAT       100000
#define NCHUNK     16
#define CHUNK_ROWS (NCAT / NCHUNK)   // 6250 rows = 1.6 MB; 16*6250 == 100000 exactly
#define NXCD       8

__global__ __launch_bounds__(256, 8) void gather_bias_relu_kernel(
    const int* __restrict__ x,
    const f32x4* __restrict__ W4,    // [100000][16]
    const f32x4* __restrict__ b4,    // [16]
    f32x4* __restrict__ out4,        // [ntok][16]
    int ntok)
{
    const int xcd          = blockIdx.x & (NXCD - 1);   // round-robin block->XCD
    const int k            = blockIdx.x >> 3;           // block index within XCD
    const int nblk_per_xcd = gridDim.x >> 3;            // 256

    // Category ranges owned by this XCD: chunks xcd and xcd+8.
    const int lo0 = xcd * CHUNK_ROWS,              hi0 = lo0 + CHUNK_ROWS;
    const int lo1 = (xcd + NXCD) * CHUNK_ROWS,     hi1 = lo1 + CHUNK_ROWS;

    // Token span for this block.
    const int span = (ntok + nblk_per_xcd - 1) / nblk_per_xcd;  // 16384
    const int t0   = k * span;
    const int t1   = min(t0 + span, ntok);

    const int   j     = threadIdx.x & 15;    // 16B slot within the 64-float row
    const f32x4 bias  = b4[j];
    const int   group = threadIdx.x >> 4;    // 16 token-groups per block

    int t = t0 + group;

    // 4-wide unrolled scan: 4 independent x loads in flight, then 4
    // group-uniform predicated gather+store blocks.
    for (; t + 48 < t1; t += 64) {
        const int ia = __builtin_nontemporal_load(&x[t]);
        const int ib = __builtin_nontemporal_load(&x[t + 16]);
        const int ic = __builtin_nontemporal_load(&x[t + 32]);
        const int id = __builtin_nontemporal_load(&x[t + 48]);

        if ((ia >= lo0 && ia < hi0) || (ia >= lo1 && ia < hi1)) {
            f32x4 w = W4[(size_t)ia * 16 + j];
            f32x4 r;
            #pragma unroll
            for (int c = 0; c < 4; ++c) r[c] = fmaxf(w[c] + bias[c], 0.0f) + 1e-5f;
            __builtin_nontemporal_store(r, &out4[(size_t)t * 16 + j]);
        }
        if ((ib >= lo0 && ib < hi0) || (ib >= lo1 && ib < hi1)) {
            f32x4 w = W4[(size_t)ib * 16 + j];
            f32x4 r;
            #pragma unroll
            for (int c = 0; c < 4; ++c) r[c] = fmaxf(w[c] + bias[c], 0.0f) + 1e-5f;
            __builtin_nontemporal_store(r, &out4[(size_t)(t + 16) * 16 + j]);
        }
        if ((ic >= lo0 && ic < hi0) || (ic >= lo1 && ic < hi1)) {
            f32x4 w = W4[(size_t)ic * 16 + j];
            f32x4 r;
            #pragma unroll
            for (int c = 0; c < 4; ++c) r[c] = fmaxf(w[c] + bias[c], 0.0f) + 1e-5f;
            __builtin_nontemporal_store(r, &out4[(size_t)(t + 32) * 16 + j]);
        }
        if ((id >= lo0 && id < hi0) || (id >= lo1 && id < hi1)) {
            f32x4 w = W4[(size_t)id * 16 + j];
            f32x4 r;
            #pragma unroll
            for (int c = 0; c < 4; ++c) r[c] = fmaxf(w[c] + bias[c], 0.0f) + 1e-5f;
            __builtin_nontemporal_store(r, &out4[(size_t)(t + 48) * 16 + j]);
        }
    }
    // Tail
    for (; t < t1; t += 16) {
        const int idx = __builtin_nontemporal_load(&x[t]);
        if ((idx >= lo0 && idx < hi0) || (idx >= lo1 && idx < hi1)) {
            f32x4 w = W4[(size_t)idx * 16 + j];
            f32x4 r;
            #pragma unroll
            for (int c = 0; c < 4; ++c) r[c] = fmaxf(w[c] + bias[c], 0.0f) + 1e-5f;
            __builtin_nontemporal_store(r, &out4[(size_t)t * 16 + j]);
        }
    }
}

extern "C" void kernel_launch(void* const* d_in, const int* in_sizes, int n_in,
                              void* d_out, int out_size, void* d_ws, size_t ws_size,
                              hipStream_t stream) {
    const int*   x   = (const int*)d_in[0];
    const float* W   = (const float*)d_in[1];
    const float* b   = (const float*)d_in[2];
    float*       out = (float*)d_out;

    const int ntok = in_sizes[0];            // 4,194,304

    const int block = 256;
    const int grid  = 2048;                  // 256 blocks per XCD, exact fill

    gather_bias_relu_kernel<<<grid, block, 0, stream>>>(
        x,
        (const f32x4*)W,
        (const f32x4*)b,
        (f32x4*)out,
        ntok);
}

// Round 7
// 226.146 us; speedup vs baseline: 14.8954x; 3.0795x over previous
//
#include <hip/hip_runtime.h>

// out[token][0:64] = relu(W[x[token]][0:64] + b[0:64]) + 1e-5
// x: int32 [4194304], W: f32 [100000][64], b: f32 [64], out: f32 [4194304][64]
//
// Two-kernel XCD-ownership gather:
//  K1 (partition): each block bucket-sorts its 2048 tokens by owning XCD
//     (idx/12500) in LDS, dumps (token,idx) pairs to per-(xcd,block) regions
//     in d_ws. Kernel boundary = free global sync (replaces R5's 3ms grid.sync).
//  K2 (gather): block b serves XCD b%8 (round-robin dispatch, confirmed by
//     R6's FETCH collapse 1.8GB->224MB). It only ever touches W rows
//     [xcd*12500,(xcd+1)*12500) = 3.2MB -> pinned in that XCD's 4MB L2 for
//     the kernel lifetime. Regions staged to LDS; every loop iteration does
//     a real gather+store (100% duty; R6's 12.5%-duty branchy scan was the
//     latency bound), 4-deep unroll for MLP. Output stores nontemporal.

typedef float f32x4 __attribute__((ext_vector_type(4)));

#define TPB   2048          // tokens per producer block
#define NXCD  8
#define PAD   512           // region capacity; mean fill 256, sigma 15 -> safe
#define ROWS_PER_XCD 12500  // 100000/8 -> 3.2 MB per XCD

__global__ __launch_bounds__(256) void partition_kernel(
    const int* __restrict__ x, int ntok,
    int*  __restrict__ counts,       // [NXCD * nblk]
    int2* __restrict__ pairs,        // [NXCD * nblk * PAD]
    const f32x4* __restrict__ W4,
    const f32x4* __restrict__ b4,
    f32x4* __restrict__ out4)
{
    __shared__ int  s_idx[TPB];
    __shared__ int2 s_pairs[TPB];
    __shared__ int  s_cnt[NXCD + 1];
    __shared__ int  s_ofs[NXCD];

    const int       tid  = threadIdx.x;
    const int       nblk = gridDim.x;
    const long long base = (long long)blockIdx.x * TPB;
    const int       n    = (int)min((long long)TPB, (long long)ntok - base);

    if (tid < NXCD + 1) s_cnt[tid] = 0;
    __syncthreads();

    for (int i = tid; i < n; i += 256) {
        const int v = x[base + i];
        s_idx[i] = v;
        atomicAdd(&s_cnt[v / ROWS_PER_XCD + 1], 1);
    }
    __syncthreads();

    if (tid == 0) {
        int acc = 0;
        #pragma unroll
        for (int c = 0; c <= NXCD; ++c) { acc += s_cnt[c]; s_cnt[c] = acc; }
    }
    __syncthreads();
    if (tid < NXCD) s_ofs[tid] = s_cnt[tid];
    __syncthreads();

    for (int i = tid; i < n; i += 256) {
        const int v = s_idx[i];
        const int c = v / ROWS_PER_XCD;
        const int p = atomicAdd(&s_ofs[c], 1);
        s_pairs[p] = make_int2((int)(base + i), v);
    }
    __syncthreads();

    for (int c = 0; c < NXCD; ++c) {
        const int s = s_cnt[c], e = s_cnt[c + 1], cnt = e - s;
        const long long rbase = ((long long)c * nblk + blockIdx.x) * PAD;
        for (int i = tid; i < cnt; i += 256) {
            if (i < PAD) {
                pairs[rbase + i] = s_pairs[s + i];
            } else {
                // overflow (never on uniform data): handle token directly
                const int2 pr = s_pairs[s + i];
                const f32x4* wr   = &W4[(size_t)pr.y * 16];
                f32x4*       orow = &out4[(size_t)pr.x * 16];
                for (int q = 0; q < 16; ++q) {
                    f32x4 w = wr[q], bb = b4[q], r;
                    #pragma unroll
                    for (int cc = 0; cc < 4; ++cc)
                        r[cc] = fmaxf(w[cc] + bb[cc], 0.0f) + 1e-5f;
                    __builtin_nontemporal_store(r, &orow[q]);
                }
            }
        }
        if (tid == 0) counts[(long long)c * nblk + blockIdx.x] = min(cnt, PAD);
    }
}

__global__ __launch_bounds__(256, 8) void gather_kernel(
    const int*  __restrict__ counts,
    const int2* __restrict__ pairs,
    const f32x4* __restrict__ W4,
    const f32x4* __restrict__ b4,
    f32x4* __restrict__ out4,
    int nblk)
{
    __shared__ int2 s_e[PAD];

    const int xcd     = blockIdx.x & (NXCD - 1);
    const int w       = blockIdx.x >> 3;
    const int workers = gridDim.x >> 3;                 // 256
    const int rpw     = (nblk + workers - 1) / workers; // 8

    const int   tid   = threadIdx.x;
    const int   j     = tid & 15;
    const f32x4 bias  = b4[j];
    const int   group = tid >> 4;

    for (int r = 0; r < rpw; ++r) {
        const int pb = w * rpw + r;
        if (pb >= nblk) break;
        const long long rec = (long long)xcd * nblk + pb;
        const int  n  = counts[rec];
        const int2* gp = &pairs[rec * PAD];

        __syncthreads();                      // previous region fully consumed
        for (int i = tid; i < n; i += 256) s_e[i] = gp[i];
        __syncthreads();

        int i = group;
        for (; i + 48 < n; i += 64) {
            const int2 e0 = s_e[i];
            const int2 e1 = s_e[i + 16];
            const int2 e2 = s_e[i + 32];
            const int2 e3 = s_e[i + 48];

            f32x4 w0 = W4[(size_t)e0.y * 16 + j];
            f32x4 w1 = W4[(size_t)e1.y * 16 + j];
            f32x4 w2 = W4[(size_t)e2.y * 16 + j];
            f32x4 w3 = W4[(size_t)e3.y * 16 + j];

            f32x4 r0, r1, r2, r3;
            #pragma unroll
            for (int c = 0; c < 4; ++c) {
                r0[c] = fmaxf(w0[c] + bias[c], 0.0f) + 1e-5f;
                r1[c] = fmaxf(w1[c] + bias[c], 0.0f) + 1e-5f;
                r2[c] = fmaxf(w2[c] + bias[c], 0.0f) + 1e-5f;
                r3[c] = fmaxf(w3[c] + bias[c], 0.0f) + 1e-5f;
            }
            __builtin_nontemporal_store(r0, &out4[(size_t)e0.x * 16 + j]);
            __builtin_nontemporal_store(r1, &out4[(size_t)e1.x * 16 + j]);
            __builtin_nontemporal_store(r2, &out4[(size_t)e2.x * 16 + j]);
            __builtin_nontemporal_store(r3, &out4[(size_t)e3.x * 16 + j]);
        }
        for (; i < n; i += 16) {
            const int2 e = s_e[i];
            f32x4 w = W4[(size_t)e.y * 16 + j];
            f32x4 rr;
            #pragma unroll
            for (int c = 0; c < 4; ++c)
                rr[c] = fmaxf(w[c] + bias[c], 0.0f) + 1e-5f;
            __builtin_nontemporal_store(rr, &out4[(size_t)e.x * 16 + j]);
        }
    }
}

// Fallback: R3's direct gather (291us) if d_ws is too small for the regions.
__global__ __launch_bounds__(256) void direct_kernel(
    const int* __restrict__ x,
    const f32x4* __restrict__ W4,
    const f32x4* __restrict__ b4,
    f32x4* __restrict__ out4,
    int ntok)
{
    const int j = threadIdx.x & 15;
    const f32x4 bias = b4[j];
    const int group   = (blockIdx.x * blockDim.x + threadIdx.x) >> 4;
    const int ngroups = (gridDim.x * blockDim.x) >> 4;
    for (int t = group; t < ntok; t += ngroups) {
        const int idx = x[t];
        f32x4 w = W4[(size_t)idx * 16 + j];
        f32x4 r;
        #pragma unroll
        for (int c = 0; c < 4; ++c)
            r[c] = fmaxf(w[c] + bias[c], 0.0f) + 1e-5f;
        __builtin_nontemporal_store(r, &out4[(size_t)t * 16 + j]);
    }
}

extern "C" void kernel_launch(void* const* d_in, const int* in_sizes, int n_in,
                              void* d_out, int out_size, void* d_ws, size_t ws_size,
                              hipStream_t stream) {
    const int*   x   = (const int*)d_in[0];
    const f32x4* W   = (const f32x4*)d_in[1];
    const f32x4* b   = (const f32x4*)d_in[2];
    f32x4*       out = (f32x4*)d_out;
    const int    ntok = in_sizes[0];                  // 4,194,304

    const int nblk = (ntok + TPB - 1) / TPB;          // 2048

    const size_t counts_bytes = (size_t)NXCD * nblk * sizeof(int);
    const size_t pairs_off    = (counts_bytes + 255) & ~(size_t)255;
    const size_t need         = pairs_off + (size_t)NXCD * nblk * PAD * sizeof(int2);

    if (ws_size >= need) {
        int*  counts = (int*)d_ws;
        int2* pairs  = (int2*)((char*)d_ws + pairs_off);

        partition_kernel<<<nblk, 256, 0, stream>>>(x, ntok, counts, pairs, W, b, out);

        const int grid2 = 2048;                       // 256 workers per XCD
        gather_kernel<<<grid2, 256, 0, stream>>>(counts, pairs, W, b, out, nblk);
    } else {
        direct_kernel<<<2048, 256, 0, stream>>>(x, W, b, out, ntok);
    }
}

// Round 8
// 221.199 us; speedup vs baseline: 15.2285x; 1.0224x over previous
//
#include <hip/hip_runtime.h>

// out[token][0:64] = relu(W[x[token]][0:64] + b[0:64]) + 1e-5
// x: int32 [4194304], W: f32 [100000][64], b: f32 [64], out: f32 [4194304][64]
//
// Two-kernel XCD-ownership gather (R7 structure, 226us):
//  K1: each block bucket-sorts its 2048 tokens by owning XCD (idx/12500),
//      dumps PACKED u32 entries (tokOff<<14 | idxInXcd) to per-(xcd,block)
//      regions in d_ws. Packing halves pair traffic vs R7's int2.
//  K2: block b serves XCD b%8; only touches W rows [xcd*12500,+12500)=3.2MB,
//      pinned in that XCD's 4MB L2. Regions double-buffered via T14
//      async-STAGE (issue loads -> process current -> ds_write -> one sync),
//      removing R7's per-region vmcnt stall. Output stores nontemporal.

typedef float f32x4 __attribute__((ext_vector_type(4)));

#define TPB   2048          // tokens per producer block
#define NXCD  8
#define PAD   512           // region capacity; mean 256, sigma 15 -> 17 sigma
#define ROWS_PER_XCD 12500  // 100000/8 -> 3.2 MB f32 per XCD

__global__ __launch_bounds__(256) void partition_kernel(
    const int* __restrict__ x, int ntok,
    int*          __restrict__ counts,   // [NXCD * nblk]
    unsigned int* __restrict__ pairs,    // [NXCD * nblk * PAD]
    const f32x4* __restrict__ W4,
    const f32x4* __restrict__ b4,
    f32x4* __restrict__ out4)
{
    __shared__ int          s_idx[TPB];
    __shared__ unsigned int s_pk[TPB];
    __shared__ int          s_cnt[NXCD + 1];
    __shared__ int          s_ofs[NXCD];

    const int       tid  = threadIdx.x;
    const int       nblk = gridDim.x;
    const long long base = (long long)blockIdx.x * TPB;
    const int       n    = (int)min((long long)TPB, (long long)ntok - base);

    if (tid < NXCD + 1) s_cnt[tid] = 0;
    __syncthreads();

    // Stage x-slab (16B vectorized when full) + histogram by owning XCD.
    if (n == TPB) {
        const int4* xs = (const int4*)(x + base);
        #pragma unroll
        for (int it = 0; it < TPB / 4 / 256; ++it) {
            const int4 v = xs[tid + it * 256];
            ((int4*)s_idx)[tid + it * 256] = v;
            atomicAdd(&s_cnt[v.x / ROWS_PER_XCD + 1], 1);
            atomicAdd(&s_cnt[v.y / ROWS_PER_XCD + 1], 1);
            atomicAdd(&s_cnt[v.z / ROWS_PER_XCD + 1], 1);
            atomicAdd(&s_cnt[v.w / ROWS_PER_XCD + 1], 1);
        }
    } else {
        for (int i = tid; i < n; i += 256) {
            const int v = x[base + i];
            s_idx[i] = v;
            atomicAdd(&s_cnt[v / ROWS_PER_XCD + 1], 1);
        }
    }
    __syncthreads();

    if (tid == 0) {
        int acc = 0;
        #pragma unroll
        for (int c = 0; c <= NXCD; ++c) { acc += s_cnt[c]; s_cnt[c] = acc; }
    }
    __syncthreads();
    if (tid < NXCD) s_ofs[tid] = s_cnt[tid];
    __syncthreads();

    // Scatter packed entries into bucket order.
    for (int i = tid; i < n; i += 256) {
        const int v = s_idx[i];
        const int c = v / ROWS_PER_XCD;
        const int p = atomicAdd(&s_ofs[c], 1);
        s_pk[p] = ((unsigned int)i << 14) | (unsigned int)(v - c * ROWS_PER_XCD);
    }
    __syncthreads();

    // Dump buckets to per-(xcd,block) regions (contiguous, coalesced).
    for (int c = 0; c < NXCD; ++c) {
        const int s = s_cnt[c], e = s_cnt[c + 1], cnt = e - s;
        const long long rbase = ((long long)c * nblk + blockIdx.x) * PAD;
        for (int i = tid; i < cnt; i += 256) {
            if (i < PAD) {
                pairs[rbase + i] = s_pk[s + i];
            } else {
                // overflow (statistically never): handle token directly
                const unsigned int pk = s_pk[s + i];
                const long long tok = base + (pk >> 14);
                const int idx = c * ROWS_PER_XCD + (int)(pk & 0x3FFFu);
                const f32x4* wr   = &W4[(size_t)idx * 16];
                f32x4*       orow = &out4[(size_t)tok * 16];
                for (int q = 0; q < 16; ++q) {
                    f32x4 w = wr[q], bb = b4[q], r;
                    #pragma unroll
                    for (int cc = 0; cc < 4; ++cc)
                        r[cc] = fmaxf(w[cc] + bb[cc], 0.0f) + 1e-5f;
                    __builtin_nontemporal_store(r, &orow[q]);
                }
            }
        }
        if (tid == 0) counts[(long long)c * nblk + blockIdx.x] = min(cnt, PAD);
    }
}

__global__ __launch_bounds__(256, 8) void gather_kernel(
    const int*          __restrict__ counts,
    const unsigned int* __restrict__ pairs,
    const f32x4* __restrict__ W4,
    const f32x4* __restrict__ b4,
    f32x4* __restrict__ out4,
    int nblk)
{
    __shared__ unsigned int s_e[2][PAD];
    __shared__ int          s_n[16];

    const int xcd     = blockIdx.x & (NXCD - 1);
    const int w       = blockIdx.x >> 3;
    const int workers = gridDim.x >> 3;                 // 256
    const int rpw     = (nblk + workers - 1) / workers; // 8

    const int   tid   = threadIdx.x;
    const int   j     = tid & 15;
    const f32x4 bias  = b4[j];
    const int   group = tid >> 4;
    const f32x4* __restrict__ Wx = W4 + (size_t)xcd * ROWS_PER_XCD * 16;

    // Stage this worker's region counts.
    if (tid < rpw) {
        const int pb = w * rpw + tid;
        s_n[tid] = (pb < nblk) ? counts[(long long)xcd * nblk + pb] : 0;
    }
    __syncthreads();

    // Prologue: stage region 0 into buffer 0.
    {
        const int pb = w * rpw;
        if (pb < nblk) {
            const unsigned int* gp = &pairs[((long long)xcd * nblk + pb) * PAD];
            const int n0 = s_n[0];
            if (tid < n0)       s_e[0][tid]       = gp[tid];
            if (tid + 256 < n0) s_e[0][tid + 256] = gp[tid + 256];
        }
    }
    __syncthreads();

    for (int r = 0; r < rpw; ++r) {
        const int pb = w * rpw + r;
        if (pb >= nblk) break;
        const int cur = r & 1;
        const int n   = s_n[r];

        // T14 async-STAGE: issue next-region loads into registers NOW;
        // ds_write them after processing (vmcnt hides under the gather).
        unsigned int st0 = 0, st1 = 0;
        int nn = 0;
        if (r + 1 < rpw && pb + 1 < nblk) {
            nn = s_n[r + 1];
            const unsigned int* gp = &pairs[((long long)xcd * nblk + pb + 1) * PAD];
            if (tid < nn)       st0 = gp[tid];
            if (tid + 256 < nn) st1 = gp[tid + 256];
        }

        const long long tokbase = (long long)pb * TPB;

        int i = group;
        for (; i + 48 < n; i += 64) {
            const unsigned int e0 = s_e[cur][i];
            const unsigned int e1 = s_e[cur][i + 16];
            const unsigned int e2 = s_e[cur][i + 32];
            const unsigned int e3 = s_e[cur][i + 48];

            f32x4 w0 = Wx[(size_t)(e0 & 0x3FFFu) * 16 + j];
            f32x4 w1 = Wx[(size_t)(e1 & 0x3FFFu) * 16 + j];
            f32x4 w2 = Wx[(size_t)(e2 & 0x3FFFu) * 16 + j];
            f32x4 w3 = Wx[(size_t)(e3 & 0x3FFFu) * 16 + j];

            f32x4 r0, r1, r2, r3;
            #pragma unroll
            for (int c = 0; c < 4; ++c) {
                r0[c] = fmaxf(w0[c] + bias[c], 0.0f) + 1e-5f;
                r1[c] = fmaxf(w1[c] + bias[c], 0.0f) + 1e-5f;
                r2[c] = fmaxf(w2[c] + bias[c], 0.0f) + 1e-5f;
                r3[c] = fmaxf(w3[c] + bias[c], 0.0f) + 1e-5f;
            }
            __builtin_nontemporal_store(r0, &out4[(tokbase + (e0 >> 14)) * 16 + j]);
            __builtin_nontemporal_store(r1, &out4[(tokbase + (e1 >> 14)) * 16 + j]);
            __builtin_nontemporal_store(r2, &out4[(tokbase + (e2 >> 14)) * 16 + j]);
            __builtin_nontemporal_store(r3, &out4[(tokbase + (e3 >> 14)) * 16 + j]);
        }
        for (; i < n; i += 16) {
            const unsigned int e = s_e[cur][i];
            f32x4 w = Wx[(size_t)(e & 0x3FFFu) * 16 + j];
            f32x4 rr;
            #pragma unroll
            for (int c = 0; c < 4; ++c)
                rr[c] = fmaxf(w[c] + bias[c], 0.0f) + 1e-5f;
            __builtin_nontemporal_store(rr, &out4[(tokbase + (e >> 14)) * 16 + j]);
        }

        // Write the prefetched region into the other buffer.
        if (tid < nn)       s_e[cur ^ 1][tid]       = st0;
        if (tid + 256 < nn) s_e[cur ^ 1][tid + 256] = st1;
        __syncthreads();
    }
}

// Fallback: direct gather (R3-style, ~300us) if d_ws is too small.
__global__ __launch_bounds__(256) void direct_kernel(
    const int* __restrict__ x,
    const f32x4* __restrict__ W4,
    const f32x4* __restrict__ b4,
    f32x4* __restrict__ out4,
    int ntok)
{
    const int j = threadIdx.x & 15;
    const f32x4 bias = b4[j];
    const int group   = (blockIdx.x * blockDim.x + threadIdx.x) >> 4;
    const int ngroups = (gridDim.x * blockDim.x) >> 4;
    for (int t = group; t < ntok; t += ngroups) {
        const int idx = x[t];
        f32x4 w = W4[(size_t)idx * 16 + j];
        f32x4 r;
        #pragma unroll
        for (int c = 0; c < 4; ++c)
            r[c] = fmaxf(w[c] + bias[c], 0.0f) + 1e-5f;
        __builtin_nontemporal_store(r, &out4[(size_t)t * 16 + j]);
    }
}

extern "C" void kernel_launch(void* const* d_in, const int* in_sizes, int n_in,
                              void* d_out, int out_size, void* d_ws, size_t ws_size,
                              hipStream_t stream) {
    const int*   x   = (const int*)d_in[0];
    const f32x4* W   = (const f32x4*)d_in[1];
    const f32x4* b   = (const f32x4*)d_in[2];
    f32x4*       out = (f32x4*)d_out;
    const int    ntok = in_sizes[0];                  // 4,194,304

    const int nblk = (ntok + TPB - 1) / TPB;          // 2048

    const size_t counts_bytes = (size_t)NXCD * nblk * sizeof(int);
    const size_t pairs_off    = (counts_bytes + 255) & ~(size_t)255;
    const size_t need         = pairs_off + (size_t)NXCD * nblk * PAD * sizeof(unsigned int);

    if (ws_size >= need) {
        int*          counts = (int*)d_ws;
        unsigned int* pairs  = (unsigned int*)((char*)d_ws + pairs_off);

        partition_kernel<<<nblk, 256, 0, stream>>>(x, ntok, counts, pairs, W, b, out);
        gather_kernel<<<2048, 256, 0, stream>>>(counts, pairs, W, b, out, nblk);
    } else {
        direct_kernel<<<2048, 256, 0, stream>>>(x, W, b, out, ntok);
    }
}